// Round 1
// baseline (450.822 us; speedup 1.0000x reference)
//
#include <hip/hip_runtime.h>
#include <math.h>

// CoAttentionLayer fp16-MFMA pipeline, round 3: fuse rel -> (qacc, kacc).
// B=128, L=512, D=256, A=64.
//
// Pipeline:
//  cvt:   Q,K -> fp16; w_rel^T, W_q^T, W_k^T -> fp16 (transposed, K-major)
//  proj:  qp = Qh@Wq, kp = Kh@Wk  (fp16 row-major + per-batch transposed)
//  qw:    qw = Qh@w_rel for ALL batches            [B*512, 256] fp16
//  fused: per (m-tile 128 q-rows, batch):
//           loop k-tiles n0=0..3:
//             tile = tanh(qw_tile @ Kh_tile^T)  (MFMA, fp32 acc)
//             tile,tileT -> LDS (fp16, XOR-swizzled)
//             qacc += tile @ kpT-frags   (reg-resident across n0)
//             kacc  = tileT @ qpT-frags  -> f32 partial to global
//           epilogue: qlogit[q] = sum_a tanh(qp+qacc)*W_qa  (shfl reduce)
//  klog:  klogit[k] = sum_a tanh(kp + sum_mt kpart)*W_ka
//  softmax over seq -> att weights (d_out tail region)
//  weighted outputs = att_w * inputs (overwrites scratch region LAST)
//
// rel/relT are never materialized: saves ~134MB scatter-amplified writes +
// ~134MB reads vs round 2, and removes the 1-wave/SIMD acc_kernel.
//
// ws layout (shorts): Qh 16.78M | Kh 16.78M | qp 4.19M | kp 4.19M | qlog/klog f32
// d_out scratch (till weight_kernel; att region starts at byte 134,217,728):
//   qw    [0,          33,554,432)
//   kpart [33,554,432, 100,663,296)   f32 [B][4][512][64]
//   qpT   [100,663,296,109,051,904)
//   kpT   [109,051,904,117,440,512)
//   wrelT [117,440,512,117,571,584)
//   WqT   [117,571,584,117,604,352)
//   WkT   [117,604,352,117,637,120)

#define SEQ 512
#define DIM 256
#define ADIM 64
#define OUT_QATT ((size_t)33554432)  // float offset of q_att_w in d_out

using hfrag = __attribute__((ext_vector_type(8))) _Float16;
using s4 = __attribute__((ext_vector_type(4))) short;
using f4 = __attribute__((ext_vector_type(4))) float;
typedef unsigned int u32;

__device__ __forceinline__ void gl_lds16(const short* g, short* l) {
  __builtin_amdgcn_global_load_lds((const __attribute__((address_space(1))) u32*)g,
                                   (__attribute__((address_space(3))) u32*)l, 16, 0, 0);
}

__device__ __forceinline__ short f2h(float x) {  // fp32 -> fp16 RNE bit pattern
  _Float16 h = (_Float16)x;
  return __builtin_bit_cast(short, h);
}
__device__ __forceinline__ float h2f(short s) {
  return (float)__builtin_bit_cast(_Float16, s);
}
__device__ __forceinline__ float tanhf_fast(float x) {
  float e = __expf(2.0f * x);
  return 1.0f - 2.0f / (e + 1.0f);
}

// ---------------- MFMA cores ----------------
// C = A @ Bt^T.  A: [>=tileM, KTOT] K-major fp16, pre-offset to tile row 0.
// Bt: [>=tileN, KTOT] K-major, pre-offset.  LDS cols XOR-swizzled by row&7.
// 256 threads = 4 waves.

template <int KTOT>
__device__ __forceinline__ void core128(const short* __restrict__ A,
                                        const short* __restrict__ Bt,
                                        short* sA, short* sB, f4 acc[4][4]) {
  const int t = threadIdx.x;
  const int lane = t & 63, wave = t >> 6;
  const int wm = (wave & 1) << 6, wn = (wave >> 1) << 6;
  const int l15 = lane & 15, qd = lane >> 4;
  const int srow = t >> 3, scol = (t & 7) << 3;
  for (int k0 = 0; k0 < KTOT; k0 += 64) {
#pragma unroll
    for (int i = 0; i < 4; i++) {
      const int row = srow + (i << 5);
      const int gcol = k0 + (scol ^ ((row & 7) << 3));
      gl_lds16(&A[(size_t)row * KTOT + gcol], &sA[t * 8 + i * 2048]);
      gl_lds16(&Bt[(size_t)row * KTOT + gcol], &sB[t * 8 + i * 2048]);
    }
    __syncthreads();
#pragma unroll
    for (int ks = 0; ks < 2; ks++) {
      hfrag af[4], bg[4];
      const int kk = (ks << 5) + (qd << 3);
#pragma unroll
      for (int i = 0; i < 4; i++) {
        const int ar = wm + (i << 4) + l15;
        const int br = wn + (i << 4) + l15;
        af[i] = *(const hfrag*)&sA[(ar << 6) + (kk ^ ((ar & 7) << 3))];
        bg[i] = *(const hfrag*)&sB[(br << 6) + (kk ^ ((br & 7) << 3))];
      }
#pragma unroll
      for (int i = 0; i < 4; i++)
#pragma unroll
        for (int j = 0; j < 4; j++)
          acc[i][j] = __builtin_amdgcn_mfma_f32_16x16x32_f16(af[i], bg[j], acc[i][j], 0, 0, 0);
    }
    __syncthreads();
  }
}

template <int KTOT>
__device__ __forceinline__ void core64(const short* __restrict__ A,
                                       const short* __restrict__ Bt,
                                       short* sA, short* sB, f4 acc[4][2]) {
  const int t = threadIdx.x;
  const int lane = t & 63, wave = t >> 6;
  const int wm = (wave & 1) << 6, wn = (wave >> 1) << 5;
  const int l15 = lane & 15, qd = lane >> 4;
  const int srow = t >> 3, scol = (t & 7) << 3;
  for (int k0 = 0; k0 < KTOT; k0 += 64) {
#pragma unroll
    for (int i = 0; i < 4; i++) {
      const int row = srow + (i << 5);
      const int gcol = k0 + (scol ^ ((row & 7) << 3));
      gl_lds16(&A[(size_t)row * KTOT + gcol], &sA[t * 8 + i * 2048]);
      if (i < 2) gl_lds16(&Bt[(size_t)row * KTOT + gcol], &sB[t * 8 + i * 2048]);
    }
    __syncthreads();
#pragma unroll
    for (int ks = 0; ks < 2; ks++) {
      hfrag af[4], bg[2];
      const int kk = (ks << 5) + (qd << 3);
#pragma unroll
      for (int i = 0; i < 4; i++) {
        const int ar = wm + (i << 4) + l15;
        af[i] = *(const hfrag*)&sA[(ar << 6) + (kk ^ ((ar & 7) << 3))];
      }
#pragma unroll
      for (int j = 0; j < 2; j++) {
        const int br = wn + (j << 4) + l15;
        bg[j] = *(const hfrag*)&sB[(br << 6) + (kk ^ ((br & 7) << 3))];
      }
#pragma unroll
      for (int i = 0; i < 4; i++)
#pragma unroll
        for (int j = 0; j < 2; j++)
          acc[i][j] = __builtin_amdgcn_mfma_f32_16x16x32_f16(af[i], bg[j], acc[i][j], 0, 0, 0);
    }
    __syncthreads();
  }
}

// ---------------- kernels ----------------

// inputs -> fp16; small weights transposed+converted
__global__ __launch_bounds__(256) void cvt_kernel(const float* __restrict__ Q,
                                                  const float* __restrict__ K,
                                                  const float* __restrict__ wrel,
                                                  const float* __restrict__ Wq,
                                                  const float* __restrict__ Wk,
                                                  short* __restrict__ Qh, short* __restrict__ Kh,
                                                  short* __restrict__ wrelT,
                                                  short* __restrict__ WqT,
                                                  short* __restrict__ WkT) {
  const int bid = blockIdx.x;
  if (bid < 32768) {
    const size_t g = ((size_t)bid << 8) + threadIdx.x;  // float4 idx, 8,388,608 total
    const int side = (int)(g >> 22);
    const size_t loc = g & 4194303;
    const float4 v = ((const float4*)(side ? K : Q))[loc];
    s4 o;
    o[0] = f2h(v.x); o[1] = f2h(v.y); o[2] = f2h(v.z); o[3] = f2h(v.w);
    *(s4*)&(side ? Kh : Qh)[loc << 2] = o;
  } else {
    const int b2 = bid - 32768;
    if (b2 < 64) {  // wrelT[e*256+d] = wrel[d*256+e], 65536 elems
      const int i = (b2 << 8) + threadIdx.x;
#pragma unroll
      for (int u = 0; u < 4; u++) {
        const int idx = (i << 2) + u;
        const int e = idx >> 8, d = idx & 255;
        wrelT[idx] = f2h(wrel[(d << 8) + e]);
      }
    } else if (b2 < 72) {  // WqT[a*256+d] = Wq[d*64+a], 16384 elems
      const int i = ((b2 - 64) << 8) + threadIdx.x;
#pragma unroll
      for (int u = 0; u < 8; u++) {
        const int idx = (i << 3) + u;
        const int a = idx >> 8, d = idx & 255;
        WqT[idx] = f2h(Wq[(d << 6) + a]);
      }
    } else if (b2 < 80) {
      const int i = ((b2 - 72) << 8) + threadIdx.x;
#pragma unroll
      for (int u = 0; u < 8; u++) {
        const int idx = (i << 3) + u;
        const int a = idx >> 8, d = idx & 255;
        WkT[idx] = f2h(Wk[(d << 6) + a]);
      }
    }
  }
}

// qp/kp = X @ W  (tile 128x64, K=256); writes row-major + per-batch transposed
__global__ __launch_bounds__(256) void proj_kernel(const short* __restrict__ Qh,
                                                   const short* __restrict__ Kh,
                                                   const short* __restrict__ WqT,
                                                   const short* __restrict__ WkT,
                                                   short* __restrict__ qp, short* __restrict__ kp,
                                                   short* __restrict__ qpT, short* __restrict__ kpT) {
  __shared__ short sA[8192];
  __shared__ short sB[4096];
  const int which = blockIdx.y;
  const short* A = which ? Kh : Qh;
  const short* Bt = which ? WkT : WqT;
  short* P = which ? kp : qp;
  short* PT = which ? kpT : qpT;
  const int m0 = blockIdx.x << 7;
  f4 acc[4][2];
  const f4 fz = {0.f, 0.f, 0.f, 0.f};
#pragma unroll
  for (int i = 0; i < 4; i++)
#pragma unroll
    for (int j = 0; j < 2; j++) acc[i][j] = fz;
  core64<256>(A + (size_t)m0 * 256, Bt, sA, sB, acc);
  const int lane = threadIdx.x & 63, wave = threadIdx.x >> 6;
  const int wm = (wave & 1) << 6, wn = (wave >> 1) << 5;
  const int l15 = lane & 15, qd = lane >> 4;
#pragma unroll
  for (int i = 0; i < 4; i++)
#pragma unroll
    for (int j = 0; j < 2; j++) {
      s4 pack;
      const int gm0 = m0 + wm + (i << 4) + (qd << 2);
      const int a = wn + (j << 4) + l15;
#pragma unroll
      for (int r = 0; r < 4; r++) {
        pack[r] = f2h(acc[i][j][r]);
        P[(size_t)(gm0 + r) * ADIM + a] = pack[r];
      }
      const int bb = gm0 >> 9, ql = gm0 & 511;
      *(s4*)&PT[((size_t)bb * ADIM + a) * SEQ + ql] = pack;
    }
}

// qw = Qh @ w_rel for ALL batches (tile 128x128, K=256)
__global__ __launch_bounds__(256) void qw_kernel(const short* __restrict__ Qh,
                                                 const short* __restrict__ WrT,
                                                 short* __restrict__ qw) {
  __shared__ short sA[8192];
  __shared__ short sB[8192];
  const int m0 = blockIdx.x << 7, n0 = blockIdx.y << 7;
  f4 acc[4][4];
  const f4 fz = {0.f, 0.f, 0.f, 0.f};
#pragma unroll
  for (int i = 0; i < 4; i++)
#pragma unroll
    for (int j = 0; j < 4; j++) acc[i][j] = fz;
  core128<256>(Qh + (size_t)m0 * 256, WrT + (size_t)n0 * 256, sA, sB, acc);
  const int lane = threadIdx.x & 63, wave = threadIdx.x >> 6;
  const int wm = (wave & 1) << 6, wn = (wave >> 1) << 6;
  const int l15 = lane & 15, qd = lane >> 4;
#pragma unroll
  for (int i = 0; i < 4; i++)
#pragma unroll
    for (int j = 0; j < 4; j++)
#pragma unroll
      for (int r = 0; r < 4; r++) {
        const int row = m0 + wm + (i << 4) + (qd << 2) + r;
        const int col = n0 + wn + (j << 4) + l15;
        qw[(size_t)row * 256 + col] = f2h(acc[i][j][r]);
      }
}

// Fused rel + qacc + kacc.  grid (4 m-tiles, 128 batches), 256 threads.
// LDS: [0,16K shorts) = core staging (sA|sB) ALIASED with tile (q-major);
//      [16K,32K shorts) = tileT (k-major).  64KB total -> 2 blocks/CU.
__global__ __launch_bounds__(256) void fused_kernel(const short* __restrict__ qw,
                                                    const short* __restrict__ Kh,
                                                    const short* __restrict__ qpT,
                                                    const short* __restrict__ kpT,
                                                    const short* __restrict__ qp,
                                                    const float* __restrict__ Wqa,
                                                    float* __restrict__ kpart,
                                                    float* __restrict__ qlog) {
  __shared__ short smem[32768];
  short* sA = smem;
  short* sB = smem + 8192;
  short* tile = smem;           // alias: valid only outside core128 phases
  short* tileT = smem + 16384;
  const int mt = blockIdx.x, b = blockIdx.y;
  const int t = threadIdx.x;
  const int lane = t & 63, wave = t >> 6;
  const int l15 = lane & 15, qd = lane >> 4;
  const int wm = (wave & 1) << 6, wn = (wave >> 1) << 6;
  const int rbase = wave << 5;  // acc-phase: wave owns rows [wave*32, wave*32+32)
  const f4 fz = {0.f, 0.f, 0.f, 0.f};

  f4 qacc[2][4];
#pragma unroll
  for (int i2 = 0; i2 < 2; i2++)
#pragma unroll
    for (int j2 = 0; j2 < 4; j2++) qacc[i2][j2] = fz;

  const short* kpT_b = kpT + ((size_t)b * ADIM) * SEQ;
  const short* qpT_b = qpT + ((size_t)b * ADIM) * SEQ;

  for (int n0 = 0; n0 < 4; n0++) {
    // --- rel tile = qw_tile @ Kh_tile^T ---
    f4 acc[4][4];
#pragma unroll
    for (int i = 0; i < 4; i++)
#pragma unroll
      for (int j = 0; j < 4; j++) acc[i][j] = fz;
    core128<256>(qw + ((size_t)b * SEQ + mt * 128) * 256,
                 Kh + ((size_t)b * SEQ + n0 * 128) * 256, sA, sB, acc);
    // --- tanh -> fp16 -> LDS tile (q-major) + tileT (k-major), swizzled ---
#pragma unroll
    for (int i = 0; i < 4; i++)
#pragma unroll
      for (int j = 0; j < 4; j++) {
        const int row0 = wm + (i << 4) + (qd << 2);
        const int col = wn + (j << 4) + l15;
        s4 pack;
#pragma unroll
        for (int r = 0; r < 4; r++) {
          const short h = f2h(tanhf_fast(acc[i][j][r]));
          pack[r] = h;
          const int row = row0 + r;
          tile[(row << 7) + (col ^ ((row & 7) << 3))] = h;
        }
        *(s4*)&tileT[(col << 7) + (row0 ^ ((col & 7) << 3))] = pack;
      }
    __syncthreads();
    // --- qacc += tile @ kpT^T ; kacc = tileT @ qpT^T  (K=128) ---
    f4 kacc[2][4];
#pragma unroll
    for (int i2 = 0; i2 < 2; i2++)
#pragma unroll
      for (int j2 = 0; j2 < 4; j2++) kacc[i2][j2] = fz;
#pragma unroll
    for (int ks = 0; ks < 4; ks++) {
      const int kkk = (ks << 5) + (qd << 3);
      hfrag aq[2], ak[2], bq[4], bk[4];
#pragma unroll
      for (int i2 = 0; i2 < 2; i2++) {
        const int ar = rbase + (i2 << 4) + l15;
        aq[i2] = *(const hfrag*)&tile[(ar << 7) + (kkk ^ ((ar & 7) << 3))];
        ak[i2] = *(const hfrag*)&tileT[(ar << 7) + (kkk ^ ((ar & 7) << 3))];
      }
#pragma unroll
      for (int j2 = 0; j2 < 4; j2++) {
        const int a = (j2 << 4) + l15;
        bq[j2] = *(const hfrag*)&kpT_b[(size_t)a * SEQ + (n0 << 7) + kkk];
        bk[j2] = *(const hfrag*)&qpT_b[(size_t)a * SEQ + (mt << 7) + kkk];
      }
#pragma unroll
      for (int i2 = 0; i2 < 2; i2++)
#pragma unroll
        for (int j2 = 0; j2 < 4; j2++) {
          qacc[i2][j2] = __builtin_amdgcn_mfma_f32_16x16x32_f16(aq[i2], bq[j2], qacc[i2][j2], 0, 0, 0);
          kacc[i2][j2] = __builtin_amdgcn_mfma_f32_16x16x32_f16(ak[i2], bk[j2], kacc[i2][j2], 0, 0, 0);
        }
    }
    // --- write kacc partial (f32, coalesced 64B runs over a) ---
#pragma unroll
    for (int i2 = 0; i2 < 2; i2++)
#pragma unroll
      for (int j2 = 0; j2 < 4; j2++) {
        const int krow = (n0 << 7) + rbase + (i2 << 4) + (qd << 2);
        const int a = (j2 << 4) + l15;
#pragma unroll
        for (int r = 0; r < 4; r++)
          kpart[((((size_t)b << 2) + mt) * SEQ + krow + r) * ADIM + a] = kacc[i2][j2][r];
      }
    __syncthreads();  // tile region reused as staging by next core128
  }
  // --- qlogit epilogue: qlog[q] = sum_a tanh(qp + qacc) * Wqa[a] ---
  float p[2][4];
#pragma unroll
  for (int i2 = 0; i2 < 2; i2++)
#pragma unroll
    for (int r = 0; r < 4; r++) p[i2][r] = 0.f;
#pragma unroll
  for (int i2 = 0; i2 < 2; i2++)
#pragma unroll
    for (int r = 0; r < 4; r++) {
      const int q = (mt << 7) + rbase + (i2 << 4) + (qd << 2) + r;
      const size_t gq = (size_t)b * SEQ + q;
#pragma unroll
      for (int j2 = 0; j2 < 4; j2++) {
        const int a = (j2 << 4) + l15;
        p[i2][r] += tanhf_fast(h2f(qp[gq * ADIM + a]) + qacc[i2][j2][r]) * Wqa[a];
      }
    }
#pragma unroll
  for (int off = 8; off; off >>= 1)
#pragma unroll
    for (int i2 = 0; i2 < 2; i2++)
#pragma unroll
      for (int r = 0; r < 4; r++) p[i2][r] += __shfl_down(p[i2][r], off, 16);
  if (l15 == 0) {
#pragma unroll
    for (int i2 = 0; i2 < 2; i2++)
#pragma unroll
      for (int r = 0; r < 4; r++) {
        const int q = (mt << 7) + rbase + (i2 << 4) + (qd << 2) + r;
        qlog[(size_t)b * SEQ + q] = p[i2][r];
      }
  }
}

// klogit: combine 4 kacc partials + kp, tanh, dot W_ka.
// grid (2 halves, 128 batches), 256 threads; lane <-> a, wave owns 64 k-rows.
__global__ __launch_bounds__(256) void klog_kernel(const float* __restrict__ kpart,
                                                   const short* __restrict__ kp,
                                                   const float* __restrict__ Wka,
                                                   float* __restrict__ klog) {
  const int half = blockIdx.x, b = blockIdx.y;
  const int t = threadIdx.x, a = t & 63, wave = t >> 6;
  const float w = Wka[a];
  const int kbase = (half << 8) + (wave << 6);
  const size_t pb = ((size_t)b << 2) * SEQ * ADIM;
  for (int it = 0; it < 64; it++) {
    const int k = kbase + it;
    const size_t base = pb + (size_t)k * ADIM + a;
    float s = kpart[base] + kpart[base + (size_t)SEQ * ADIM] +
              kpart[base + (size_t)2 * SEQ * ADIM] + kpart[base + (size_t)3 * SEQ * ADIM];
    s = tanhf_fast(s + h2f(kp[((size_t)b * SEQ + k) * ADIM + a])) * w;
#pragma unroll
    for (int off = 32; off; off >>= 1) s += __shfl_xor(s, off);
    if (a == 0) klog[(size_t)b * SEQ + k] = s;
  }
}

// softmax over seq dim -> att weights in d_out tail
__global__ __launch_bounds__(256) void softmax_kernel(const float* __restrict__ qlog,
                                                      const float* __restrict__ klog,
                                                      float* __restrict__ out) {
  const int bx = blockIdx.x;  // 0..255
  const int side = bx >> 7;
  const int b = bx & 127;
  const float* lg = (side ? klog : qlog) + (size_t)b * SEQ;
  float* o = out + OUT_QATT + (size_t)side * (128 * SEQ) + (size_t)b * SEQ;
  const int t = threadIdx.x;
  float v0 = lg[t];
  float v1 = lg[t + 256];
  float m = fmaxf(v0, v1);
#pragma unroll
  for (int off = 32; off; off >>= 1) m = fmaxf(m, __shfl_xor(m, off));
  __shared__ float sm[4], ss[4];
  const int w = t >> 6, l = t & 63;
  if (l == 0) sm[w] = m;
  __syncthreads();
  m = fmaxf(fmaxf(sm[0], sm[1]), fmaxf(sm[2], sm[3]));
  float e0 = expf(v0 - m), e1 = expf(v1 - m);
  float s = e0 + e1;
#pragma unroll
  for (int off = 32; off; off >>= 1) s += __shfl_xor(s, off);
  if (l == 0) ss[w] = s;
  __syncthreads();
  s = ss[0] + ss[1] + ss[2] + ss[3];
  float inv = 1.0f / s;
  o[t] = e0 * inv;
  o[t + 256] = e1 * inv;
}

// weighted_* = att_w * inputs (runs LAST: overwrites the scratch region)
__global__ __launch_bounds__(256) void weight_kernel(const float* __restrict__ queries,
                                                     const float* __restrict__ keys,
                                                     float* __restrict__ out) {
  const size_t g = (size_t)blockIdx.x * 256 + threadIdx.x;  // float4 index
  const int side = (int)(g >> 22);
  const size_t loc = g & 4194303;
  const size_t row = loc >> 6;
  const float* aw = out + OUT_QATT + (size_t)side * (128 * SEQ);
  const float4* src = (const float4*)(side ? keys : queries);
  const float w = aw[row];
  float4 v = src[loc];
  float4 r = {v.x * w, v.y * w, v.z * w, v.w * w};
  ((float4*)out)[g] = r;
}

extern "C" void kernel_launch(void* const* d_in, const int* in_sizes, int n_in,
                              void* d_out, int out_size, void* d_ws, size_t ws_size,
                              hipStream_t stream) {
  const float* queries = (const float*)d_in[0];
  const float* keys = (const float*)d_in[1];
  const float* w_rel = (const float*)d_in[2];
  const float* W_q = (const float*)d_in[3];
  const float* W_k = (const float*)d_in[4];
  const float* W_qa = (const float*)d_in[5];
  const float* W_ka = (const float*)d_in[6];
  float* out = (float*)d_out;

  // ws layout (shorts / floats)
  short* Qh = (short*)d_ws;
  short* Kh = Qh + 16777216;
  short* qp = Kh + 16777216;
  short* kp = qp + 4194304;
  float* qlog = (float*)(kp + 4194304);
  float* klog = qlog + 65536;

  // d_out scratch (safe until weight_kernel; att region starts at 134,217,728)
  char* ob = (char*)d_out;
  short* qw_s = (short*)ob;                    // 33,554,432 B
  float* kpart = (float*)(ob + 33554432);      // 67,108,864 B
  short* qpT = (short*)(ob + 100663296);       // 8,388,608 B
  short* kpT = (short*)(ob + 109051904);       // 8,388,608 B
  short* wrelT = (short*)(ob + 117440512);     // 131,072 B
  short* WqT = (short*)(ob + 117571584);       // 32,768 B
  short* WkT = (short*)(ob + 117604352);       // 32,768 B

  cvt_kernel<<<32848, 256, 0, stream>>>(queries, keys, w_rel, W_q, W_k, Qh, Kh, wrelT, WqT, WkT);
  proj_kernel<<<dim3(512, 2), 256, 0, stream>>>(Qh, Kh, WqT, WkT, qp, kp, qpT, kpT);
  qw_kernel<<<dim3(512, 2), 256, 0, stream>>>(Qh, wrelT, qw_s);
  fused_kernel<<<dim3(4, 128), 256, 0, stream>>>(qw_s, Kh, qpT, kpT, qp, W_qa, kpart, qlog);
  klog_kernel<<<dim3(2, 128), 256, 0, stream>>>(kpart, kp, W_ka, klog);
  softmax_kernel<<<256, 256, 0, stream>>>(qlog, klog, out);
  weight_kernel<<<32768, 256, 0, stream>>>(queries, keys, out);
}

// Round 2
// 442.794 us; speedup vs baseline: 1.0181x; 1.0181x over previous
//
#include <hip/hip_runtime.h>
#include <math.h>

// CoAttentionLayer fp16-MFMA pipeline, round 4: symmetric dual-side kernels.
// B=128, L=512, D=256, A=64.
//
// Pipeline:
//  cvt:   Q,K -> fp16; w_rel^T, W_q^T, W_k^T -> fp16 (transposed, K-major)
//  proj:  qp = Qh@Wq, kp = Kh@Wk  (fp16 row-major + per-batch transposed)
//  qw:    qw = Qh@w_rel for ALL batches            [B*512, 256] fp16
//  side (z=0, Q): per (64-q-row tile, b):
//     A = qw tile (64x256) RESIDENT in LDS (loaded once);
//     loop n0=0..3: rel subtile = qw_tile @ Kh[n0]^T (B streamed via LDS),
//       tanh -> LDS tile; qacc += tile @ kpT-frags (in-reg across n0);
//     epilogue: qlog[q] = sum_a tanh(qp+qacc)*W_qa  (shfl reduce)
//  side (z=1, K): SAME code, A = Kh tile -> computes rel^T = Kh@qw^T directly;
//     kacc += tileT-free (rel^T is already k-major); epilogue -> klog.
//  softmax over seq -> att weights (d_out tail region)
//  weighted outputs = att_w * inputs (overwrites scratch region LAST)
//
// vs round 3: rel recomputed once per side (+17 GF, ~10us MFMA) buys:
//  - no tileT transposed LDS store (1M bank conflicts gone)
//  - no kpart 67MB write + 67MB klog re-read, no klog kernel
//  - A-tile resident: qw/Kh fetched once (round-3 fused re-read A 4x)
//  - LDS 48KB + VGPR<=128 -> 3 blocks/CU, 12 waves/CU (vs 8)
//
// ws layout (shorts): Qh 16.78M | Kh 16.78M | qp 4.19M | kp 4.19M | qlog/klog f32
// d_out scratch (till weight_kernel; att region starts at byte 134,217,728):
//   qw    [0,          33,554,432)
//   qpT   [100,663,296,109,051,904)
//   kpT   [109,051,904,117,440,512)
//   wrelT [117,440,512,117,571,584)
//   WqT   [117,571,584,117,604,352)
//   WkT   [117,604,352,117,637,120)

#define SEQ 512
#define DIM 256
#define ADIM 64
#define OUT_QATT ((size_t)33554432)  // float offset of q_att_w in d_out

using hfrag = __attribute__((ext_vector_type(8))) _Float16;
using s4 = __attribute__((ext_vector_type(4))) short;
using f4 = __attribute__((ext_vector_type(4))) float;
typedef unsigned int u32;

__device__ __forceinline__ void gl_lds16(const short* g, short* l) {
  __builtin_amdgcn_global_load_lds((const __attribute__((address_space(1))) u32*)g,
                                   (__attribute__((address_space(3))) u32*)l, 16, 0, 0);
}

__device__ __forceinline__ short f2h(float x) {  // fp32 -> fp16 RNE bit pattern
  _Float16 h = (_Float16)x;
  return __builtin_bit_cast(short, h);
}
__device__ __forceinline__ float h2f(short s) {
  return (float)__builtin_bit_cast(_Float16, s);
}
__device__ __forceinline__ float tanhf_fast(float x) {
  float e = __expf(2.0f * x);
  return 1.0f - 2.0f / (e + 1.0f);
}

// ---------------- MFMA core (for proj/qw): C = A @ Bt^T ----------------
// A: [>=tileM, KTOT] K-major fp16, pre-offset. Bt: [>=tileN, KTOT] K-major.
// LDS cols XOR-swizzled by row&7.  256 threads = 4 waves.

template <int KTOT>
__device__ __forceinline__ void core128(const short* __restrict__ A,
                                        const short* __restrict__ Bt,
                                        short* sA, short* sB, f4 acc[4][4]) {
  const int t = threadIdx.x;
  const int lane = t & 63, wave = t >> 6;
  const int wm = (wave & 1) << 6, wn = (wave >> 1) << 6;
  const int l15 = lane & 15, qd = lane >> 4;
  const int srow = t >> 3, scol = (t & 7) << 3;
  for (int k0 = 0; k0 < KTOT; k0 += 64) {
#pragma unroll
    for (int i = 0; i < 4; i++) {
      const int row = srow + (i << 5);
      const int gcol = k0 + (scol ^ ((row & 7) << 3));
      gl_lds16(&A[(size_t)row * KTOT + gcol], &sA[t * 8 + i * 2048]);
      gl_lds16(&Bt[(size_t)row * KTOT + gcol], &sB[t * 8 + i * 2048]);
    }
    __syncthreads();
#pragma unroll
    for (int ks = 0; ks < 2; ks++) {
      hfrag af[4], bg[4];
      const int kk = (ks << 5) + (qd << 3);
#pragma unroll
      for (int i = 0; i < 4; i++) {
        const int ar = wm + (i << 4) + l15;
        const int br = wn + (i << 4) + l15;
        af[i] = *(const hfrag*)&sA[(ar << 6) + (kk ^ ((ar & 7) << 3))];
        bg[i] = *(const hfrag*)&sB[(br << 6) + (kk ^ ((br & 7) << 3))];
      }
#pragma unroll
      for (int i = 0; i < 4; i++)
#pragma unroll
        for (int j = 0; j < 4; j++)
          acc[i][j] = __builtin_amdgcn_mfma_f32_16x16x32_f16(af[i], bg[j], acc[i][j], 0, 0, 0);
    }
    __syncthreads();
  }
}

template <int KTOT>
__device__ __forceinline__ void core64(const short* __restrict__ A,
                                       const short* __restrict__ Bt,
                                       short* sA, short* sB, f4 acc[4][2]) {
  const int t = threadIdx.x;
  const int lane = t & 63, wave = t >> 6;
  const int wm = (wave & 1) << 6, wn = (wave >> 1) << 5;
  const int l15 = lane & 15, qd = lane >> 4;
  const int srow = t >> 3, scol = (t & 7) << 3;
  for (int k0 = 0; k0 < KTOT; k0 += 64) {
#pragma unroll
    for (int i = 0; i < 4; i++) {
      const int row = srow + (i << 5);
      const int gcol = k0 + (scol ^ ((row & 7) << 3));
      gl_lds16(&A[(size_t)row * KTOT + gcol], &sA[t * 8 + i * 2048]);
      if (i < 2) gl_lds16(&Bt[(size_t)row * KTOT + gcol], &sB[t * 8 + i * 2048]);
    }
    __syncthreads();
#pragma unroll
    for (int ks = 0; ks < 2; ks++) {
      hfrag af[4], bg[2];
      const int kk = (ks << 5) + (qd << 3);
#pragma unroll
      for (int i = 0; i < 4; i++) {
        const int ar = wm + (i << 4) + l15;
        af[i] = *(const hfrag*)&sA[(ar << 6) + (kk ^ ((ar & 7) << 3))];
      }
#pragma unroll
      for (int j = 0; j < 2; j++) {
        const int br = wn + (j << 4) + l15;
        bg[j] = *(const hfrag*)&sB[(br << 6) + (kk ^ ((br & 7) << 3))];
      }
#pragma unroll
      for (int i = 0; i < 4; i++)
#pragma unroll
        for (int j = 0; j < 2; j++)
          acc[i][j] = __builtin_amdgcn_mfma_f32_16x16x32_f16(af[i], bg[j], acc[i][j], 0, 0, 0);
    }
    __syncthreads();
  }
}

// ---------------- kernels ----------------

// inputs -> fp16; small weights transposed+converted
__global__ __launch_bounds__(256) void cvt_kernel(const float* __restrict__ Q,
                                                  const float* __restrict__ K,
                                                  const float* __restrict__ wrel,
                                                  const float* __restrict__ Wq,
                                                  const float* __restrict__ Wk,
                                                  short* __restrict__ Qh, short* __restrict__ Kh,
                                                  short* __restrict__ wrelT,
                                                  short* __restrict__ WqT,
                                                  short* __restrict__ WkT) {
  const int bid = blockIdx.x;
  if (bid < 32768) {
    const size_t g = ((size_t)bid << 8) + threadIdx.x;  // float4 idx, 8,388,608 total
    const int side = (int)(g >> 22);
    const size_t loc = g & 4194303;
    const float4 v = ((const float4*)(side ? K : Q))[loc];
    s4 o;
    o[0] = f2h(v.x); o[1] = f2h(v.y); o[2] = f2h(v.z); o[3] = f2h(v.w);
    *(s4*)&(side ? Kh : Qh)[loc << 2] = o;
  } else {
    const int b2 = bid - 32768;
    if (b2 < 64) {  // wrelT[e*256+d] = wrel[d*256+e], 65536 elems
      const int i = (b2 << 8) + threadIdx.x;
#pragma unroll
      for (int u = 0; u < 4; u++) {
        const int idx = (i << 2) + u;
        const int e = idx >> 8, d = idx & 255;
        wrelT[idx] = f2h(wrel[(d << 8) + e]);
      }
    } else if (b2 < 72) {  // WqT[a*256+d] = Wq[d*64+a], 16384 elems
      const int i = ((b2 - 64) << 8) + threadIdx.x;
#pragma unroll
      for (int u = 0; u < 8; u++) {
        const int idx = (i << 3) + u;
        const int a = idx >> 8, d = idx & 255;
        WqT[idx] = f2h(Wq[(d << 6) + a]);
      }
    } else if (b2 < 80) {
      const int i = ((b2 - 72) << 8) + threadIdx.x;
#pragma unroll
      for (int u = 0; u < 8; u++) {
        const int idx = (i << 3) + u;
        const int a = idx >> 8, d = idx & 255;
        WkT[idx] = f2h(Wk[(d << 6) + a]);
      }
    }
  }
}

// qp/kp = X @ W  (tile 128x64, K=256); writes row-major + per-batch transposed
__global__ __launch_bounds__(256) void proj_kernel(const short* __restrict__ Qh,
                                                   const short* __restrict__ Kh,
                                                   const short* __restrict__ WqT,
                                                   const short* __restrict__ WkT,
                                                   short* __restrict__ qp, short* __restrict__ kp,
                                                   short* __restrict__ qpT, short* __restrict__ kpT) {
  __shared__ short sA[8192];
  __shared__ short sB[4096];
  const int which = blockIdx.y;
  const short* A = which ? Kh : Qh;
  const short* Bt = which ? WkT : WqT;
  short* P = which ? kp : qp;
  short* PT = which ? kpT : qpT;
  const int m0 = blockIdx.x << 7;
  f4 acc[4][2];
  const f4 fz = {0.f, 0.f, 0.f, 0.f};
#pragma unroll
  for (int i = 0; i < 4; i++)
#pragma unroll
    for (int j = 0; j < 2; j++) acc[i][j] = fz;
  core64<256>(A + (size_t)m0 * 256, Bt, sA, sB, acc);
  const int lane = threadIdx.x & 63, wave = threadIdx.x >> 6;
  const int wm = (wave & 1) << 6, wn = (wave >> 1) << 5;
  const int l15 = lane & 15, qd = lane >> 4;
#pragma unroll
  for (int i = 0; i < 4; i++)
#pragma unroll
    for (int j = 0; j < 2; j++) {
      s4 pack;
      const int gm0 = m0 + wm + (i << 4) + (qd << 2);
      const int a = wn + (j << 4) + l15;
#pragma unroll
      for (int r = 0; r < 4; r++) {
        pack[r] = f2h(acc[i][j][r]);
        P[(size_t)(gm0 + r) * ADIM + a] = pack[r];
      }
      const int bb = gm0 >> 9, ql = gm0 & 511;
      *(s4*)&PT[((size_t)bb * ADIM + a) * SEQ + ql] = pack;
    }
}

// qw = Qh @ w_rel for ALL batches (tile 128x128, K=256)
__global__ __launch_bounds__(256) void qw_kernel(const short* __restrict__ Qh,
                                                 const short* __restrict__ WrT,
                                                 short* __restrict__ qw) {
  __shared__ short sA[8192];
  __shared__ short sB[8192];
  const int m0 = blockIdx.x << 7, n0 = blockIdx.y << 7;
  f4 acc[4][4];
  const f4 fz = {0.f, 0.f, 0.f, 0.f};
#pragma unroll
  for (int i = 0; i < 4; i++)
#pragma unroll
    for (int j = 0; j < 4; j++) acc[i][j] = fz;
  core128<256>(Qh + (size_t)m0 * 256, WrT + (size_t)n0 * 256, sA, sB, acc);
  const int lane = threadIdx.x & 63, wave = threadIdx.x >> 6;
  const int wm = (wave & 1) << 6, wn = (wave >> 1) << 6;
  const int l15 = lane & 15, qd = lane >> 4;
#pragma unroll
  for (int i = 0; i < 4; i++)
#pragma unroll
    for (int j = 0; j < 4; j++)
#pragma unroll
      for (int r = 0; r < 4; r++) {
        const int row = m0 + wm + (i << 4) + (qd << 2) + r;
        const int col = n0 + wn + (j << 4) + l15;
        qw[(size_t)row * 256 + col] = f2h(acc[i][j][r]);
      }
}

// Symmetric side kernel. grid (8 row-tiles, 128 batches, 2 sides), 256 thr.
// z=0 (Q side): Ares=qw rows q,  Bstream=Kh rows k, pT=kpT, prow=qp, W=W_qa -> qlog
// z=1 (K side): Ares=Kh rows k,  Bstream=qw rows q, pT=qpT, prow=kp, W=W_ka -> klog
// Per block: A 64x256 resident LDS; loop nt=0..3: rel(^T) subtile 64x128 via
// MFMA, tanh->LDS; acc += tile @ pT-frags (in-reg, K accumulated over nt);
// epilogue: logit = (tanh(prow + acc) @ W) via shfl reduce.
// LDS 48KB (A 32K + Bstage/tile 16K alias); VGPR<=128 -> 3 blocks/CU.
__global__ __launch_bounds__(256, 4) void side_kernel(const short* __restrict__ qw,
                                                      const short* __restrict__ Kh,
                                                      const short* __restrict__ qpT,
                                                      const short* __restrict__ kpT,
                                                      const short* __restrict__ qp,
                                                      const short* __restrict__ kp,
                                                      const float* __restrict__ Wqa,
                                                      const float* __restrict__ Wka,
                                                      float* __restrict__ qlog,
                                                      float* __restrict__ klog) {
  __shared__ short sA[16384];  // 64 rows x 256, swizzled
  __shared__ short sB[8192];   // B stage 128x64 / tanh tile 64x128 (alias)
  const int sideK = blockIdx.z;
  const short* Asrc = sideK ? Kh : qw;
  const short* Bsrc = sideK ? qw : Kh;
  const short* pT = sideK ? qpT : kpT;
  const short* prow = sideK ? kp : qp;
  const float* Watt = sideK ? Wka : Wqa;
  float* logit = sideK ? klog : qlog;

  const int tt = blockIdx.x;  // 64-row tile index (0..7)
  const int b = blockIdx.y;
  const int t = threadIdx.x;
  const int lane = t & 63, wave = t >> 6;
  const int l15 = lane & 15, qd = lane >> 4;
  const int wm = (wave & 1) << 5, wn = (wave >> 1) << 6;
  const f4 fz = {0.f, 0.f, 0.f, 0.f};

  // --- load A resident (64x256), pre-swizzled global cols, linear LDS dest ---
  {
    const short* Ag = Asrc + ((size_t)b * SEQ + tt * 64) * DIM;
    const int chunk = t & 31;   // 16B chunk within a row
    const int rb = t >> 5;      // 0..7
#pragma unroll
    for (int i = 0; i < 8; i++) {
      const int row = (i << 3) + rb;
      const int gcol = (chunk << 3) ^ ((row & 7) << 3);
      gl_lds16(&Ag[(size_t)row * DIM + gcol], &sA[(row << 8) + (chunk << 3)]);
    }
  }

  f4 pacc[4];  // [64 rows x 64 a] per wave: 16 rows, j2 over 4 a-blocks
#pragma unroll
  for (int j = 0; j < 4; j++) pacc[j] = fz;

  const short* pT_b = pT + (size_t)b * ADIM * SEQ;
  const int srow = t >> 3, scol = (t & 7) << 3;

  for (int n0 = 0; n0 < 4; n0++) {
    // --- rel subtile = Ares @ Bstream[n0]^T   (64 x 128, K=256) ---
    f4 acc[2][4];
#pragma unroll
    for (int i = 0; i < 2; i++)
#pragma unroll
      for (int j = 0; j < 4; j++) acc[i][j] = fz;
    const short* Bg = Bsrc + ((size_t)b * SEQ + n0 * 128) * DIM;
    for (int k0 = 0; k0 < 256; k0 += 64) {
#pragma unroll
      for (int i = 0; i < 4; i++) {
        const int row = srow + (i << 5);
        const int gcol = k0 + (scol ^ ((row & 7) << 3));
        gl_lds16(&Bg[(size_t)row * DIM + gcol], &sB[t * 8 + i * 2048]);
      }
      __syncthreads();
#pragma unroll
      for (int ks = 0; ks < 2; ks++) {
        const int kkB = (ks << 5) + (qd << 3);
        const int kkA = k0 + kkB;
        hfrag af[2], bg[4];
#pragma unroll
        for (int i = 0; i < 2; i++) {
          const int ar = wm + (i << 4) + l15;
          af[i] = *(const hfrag*)&sA[(ar << 8) + (kkA ^ ((ar & 7) << 3))];
        }
#pragma unroll
        for (int j = 0; j < 4; j++) {
          const int br = wn + (j << 4) + l15;
          bg[j] = *(const hfrag*)&sB[(br << 6) + (kkB ^ ((br & 7) << 3))];
        }
#pragma unroll
        for (int i = 0; i < 2; i++)
#pragma unroll
          for (int j = 0; j < 4; j++)
            acc[i][j] = __builtin_amdgcn_mfma_f32_16x16x32_f16(af[i], bg[j], acc[i][j], 0, 0, 0);
      }
      __syncthreads();
    }
    // --- tanh -> fp16 tile (64x128) into sB (staging done for this n0) ---
#pragma unroll
    for (int i = 0; i < 2; i++)
#pragma unroll
      for (int j = 0; j < 4; j++) {
        const int row0 = wm + (i << 4) + (qd << 2);
        const int col = wn + (j << 4) + l15;
#pragma unroll
        for (int r = 0; r < 4; r++) {
          const int row = row0 + r;
          sB[(row << 7) + (col ^ ((row & 7) << 3))] = f2h(tanhf_fast(acc[i][j][r]));
        }
      }
    __syncthreads();
    // --- pacc += tile @ pT-frags  (K = this n0's 128) ---
#pragma unroll
    for (int ks = 0; ks < 4; ks++) {
      const int kkk = (ks << 5) + (qd << 3);
      const int ar = (wave << 4) + l15;
      const hfrag aq = *(const hfrag*)&sB[(ar << 7) + (kkk ^ ((ar & 7) << 3))];
#pragma unroll
      for (int j2 = 0; j2 < 4; j2++) {
        const int a = (j2 << 4) + l15;
        const hfrag bq = *(const hfrag*)&pT_b[(size_t)a * SEQ + (n0 << 7) + kkk];
        pacc[j2] = __builtin_amdgcn_mfma_f32_16x16x32_f16(aq, bq, pacc[j2], 0, 0, 0);
      }
    }
    __syncthreads();  // protect sB before next n0's staging
  }

  // --- epilogue: logit[row] = sum_a tanh(prow + pacc) * Watt[a] ---
  const int row_l = (wave << 4) + (qd << 2);
  const size_t g0 = (size_t)b * SEQ + tt * 64 + row_l;
  float p[4] = {0.f, 0.f, 0.f, 0.f};
#pragma unroll
  for (int r = 0; r < 4; r++)
#pragma unroll
    for (int j2 = 0; j2 < 4; j2++) {
      const int a = (j2 << 4) + l15;
      p[r] += tanhf_fast(h2f(prow[(g0 + r) * ADIM + a]) + pacc[j2][r]) * Watt[a];
    }
#pragma unroll
  for (int off = 8; off; off >>= 1)
#pragma unroll
    for (int r = 0; r < 4; r++) p[r] += __shfl_down(p[r], off, 16);
  if (l15 == 0) {
#pragma unroll
    for (int r = 0; r < 4; r++) logit[g0 + r] = p[r];
  }
}

// softmax over seq dim -> att weights in d_out tail
__global__ __launch_bounds__(256) void softmax_kernel(const float* __restrict__ qlog,
                                                      const float* __restrict__ klog,
                                                      float* __restrict__ out) {
  const int bx = blockIdx.x;  // 0..255
  const int side = bx >> 7;
  const int b = bx & 127;
  const float* lg = (side ? klog : qlog) + (size_t)b * SEQ;
  float* o = out + OUT_QATT + (size_t)side * (128 * SEQ) + (size_t)b * SEQ;
  const int t = threadIdx.x;
  float v0 = lg[t];
  float v1 = lg[t + 256];
  float m = fmaxf(v0, v1);
#pragma unroll
  for (int off = 32; off; off >>= 1) m = fmaxf(m, __shfl_xor(m, off));
  __shared__ float sm[4], ss[4];
  const int w = t >> 6, l = t & 63;
  if (l == 0) sm[w] = m;
  __syncthreads();
  m = fmaxf(fmaxf(sm[0], sm[1]), fmaxf(sm[2], sm[3]));
  float e0 = expf(v0 - m), e1 = expf(v1 - m);
  float s = e0 + e1;
#pragma unroll
  for (int off = 32; off; off >>= 1) s += __shfl_xor(s, off);
  if (l == 0) ss[w] = s;
  __syncthreads();
  s = ss[0] + ss[1] + ss[2] + ss[3];
  float inv = 1.0f / s;
  o[t] = e0 * inv;
  o[t + 256] = e1 * inv;
}

// weighted_* = att_w * inputs (runs LAST: overwrites the scratch region)
__global__ __launch_bounds__(256) void weight_kernel(const float* __restrict__ queries,
                                                     const float* __restrict__ keys,
                                                     float* __restrict__ out) {
  const size_t g = (size_t)blockIdx.x * 256 + threadIdx.x;  // float4 index
  const int side = (int)(g >> 22);
  const size_t loc = g & 4194303;
  const size_t row = loc >> 6;
  const float* aw = out + OUT_QATT + (size_t)side * (128 * SEQ);
  const float4* src = (const float4*)(side ? keys : queries);
  const float w = aw[row];
  float4 v = src[loc];
  float4 r = {v.x * w, v.y * w, v.z * w, v.w * w};
  ((float4*)out)[g] = r;
}

extern "C" void kernel_launch(void* const* d_in, const int* in_sizes, int n_in,
                              void* d_out, int out_size, void* d_ws, size_t ws_size,
                              hipStream_t stream) {
  const float* queries = (const float*)d_in[0];
  const float* keys = (const float*)d_in[1];
  const float* w_rel = (const float*)d_in[2];
  const float* W_q = (const float*)d_in[3];
  const float* W_k = (const float*)d_in[4];
  const float* W_qa = (const float*)d_in[5];
  const float* W_ka = (const float*)d_in[6];
  float* out = (float*)d_out;

  // ws layout (shorts / floats)
  short* Qh = (short*)d_ws;
  short* Kh = Qh + 16777216;
  short* qp = Kh + 16777216;
  short* kp = qp + 4194304;
  float* qlog = (float*)(kp + 4194304);
  float* klog = qlog + 65536;

  // d_out scratch (safe until weight_kernel; att region starts at 134,217,728)
  char* ob = (char*)d_out;
  short* qw_s = (short*)ob;                    // 33,554,432 B
  short* qpT = (short*)(ob + 100663296);       // 8,388,608 B
  short* kpT = (short*)(ob + 109051904);       // 8,388,608 B
  short* wrelT = (short*)(ob + 117440512);     // 131,072 B
  short* WqT = (short*)(ob + 117571584);       // 32,768 B
  short* WkT = (short*)(ob + 117604352);       // 32,768 B

  cvt_kernel<<<32848, 256, 0, stream>>>(queries, keys, w_rel, W_q, W_k, Qh, Kh, wrelT, WqT, WkT);
  proj_kernel<<<dim3(512, 2), 256, 0, stream>>>(Qh, Kh, WqT, WkT, qp, kp, qpT, kpT);
  qw_kernel<<<dim3(512, 2), 256, 0, stream>>>(Qh, wrelT, qw_s);
  side_kernel<<<dim3(8, 128, 2), 256, 0, stream>>>(qw_s, Kh, qpT, kpT, qp, kp, W_qa, W_ka, qlog, klog);
  softmax_kernel<<<256, 256, 0, stream>>>(qlog, klog, out);
  weight_kernel<<<32768, 256, 0, stream>>>(queries, keys, out);
}